// Round 6
// baseline (380.869 us; speedup 1.0000x reference)
//
#include <hip/hip_runtime.h>

// Caps layer: B=256 batches, S=512 input caps, D=256 in-dim, NC=16, DC=32, O=512.
// One block per batch, 512 threads (8 waves); grid 256 = 1 block/CU.
// Fully-fused factorized routing (u_hat and full b never materialized):
//   per routing iter (single x-stream):  per 16-s tile:
//     b_tile[16n x 16s] = z * x^T        (MFMA 16x16x32 bf16, fp32 acc)
//     c_tile = softmax_n(b_tile)         (4-lane shfl over C-fragment)
//     y[n][D] += sum_{s in tile} c[n][s] x[s][D]   (x re-read is L1/L2-hot)
//   then: outputs = squash(y . W), z = W . outputs, repeat.
// x streamed exactly 3x (iter0 rowsum + 2 fused passes) - algorithmic minimum.

#define S_ 512
#define D_ 256
#define O_ 512

typedef __attribute__((ext_vector_type(8))) short short8;
typedef __attribute__((ext_vector_type(4))) float floatx4;

__device__ __forceinline__ unsigned short f2b(float f) {
  union { float ff; unsigned int i; } v; v.ff = f;
  unsigned int u = v.i;
  return (unsigned short)((u + 0x7FFFu + ((u >> 16) & 1u)) >> 16);
}

__global__ __launch_bounds__(512, 2) void caps_kernel(
    const float* __restrict__ x, const float* __restrict__ W,
    float* __restrict__ out)
{
  // LDS (~35 KB):
  //   bl   f32 8x256  =  8192 B: per-wave ctileT[16s][16n] | iter0 rowsum strips
  //   ytmp f32 16x260 = 16640 B: y[n][D] (ds_add reduction target)
  //   zb   u16 16x264 =  8448 B: z bf16 (528 B rows, 16B-aligned)
  //   outp f32 512    =  2048 B
  __shared__ __align__(16) float bl[8 * 256];
  __shared__ __align__(16) float ytmp[16 * 260];
  __shared__ __align__(16) unsigned short zb[16 * 264];
  __shared__ __align__(16) float outp[O_];

  const int tid  = threadIdx.x;
  const int wave = tid >> 6;
  const int lane = tid & 63;
  const int l15  = lane & 15, l4 = lane >> 4;
  const float* xb = x + (size_t)blockIdx.x * (S_ * D_);
  float* ct = bl + wave * 256;   // per-wave c-tile [16s][16n] f32

  for (int it = 0; it < 3; ++it) {
    if (it == 0) {
      // ---- iter 0: b=0 -> c=1/16 -> y[n][:] = (1/16)*rowsum(x), all n equal ----
      float a0 = 0.f, a1 = 0.f, a2 = 0.f, a3 = 0.f;
      #pragma unroll 4
      for (int r = 0; r < 64; ++r) {
        const int s = (wave << 6) + r;
        const float4 xv = *(const float4*)(xb + s * D_ + (lane << 2));
        a0 += xv.x; a1 += xv.y; a2 += xv.z; a3 += xv.w;
      }
      *(float4*)(bl + wave * 256 + (lane << 2)) = make_float4(a0, a1, a2, a3);
      __syncthreads();
      if (tid < 256) {
        float v = 0.f;
        #pragma unroll
        for (int w = 0; w < 8; ++w) v += bl[w * 256 + tid];
        v *= 0.0625f;
        #pragma unroll
        for (int n = 0; n < 16; ++n) ytmp[n * 260 + tid] = v;
      }
      __syncthreads();
    } else {
      // ---- fused pass: MFMA b-tile -> softmax -> y-accum; single x stream ----
      for (int i = tid; i < 16 * 260; i += 512) ytmp[i] = 0.f;
      __syncthreads();

      float yacc[16][4];
      #pragma unroll
      for (int n = 0; n < 16; ++n) { yacc[n][0]=0.f; yacc[n][1]=0.f; yacc[n][2]=0.f; yacc[n][3]=0.f; }

      for (int t = 0; t < 4; ++t) {
        const int s0 = (wave << 6) + (t << 4);
        // --- b tile: b[n][s] = sum_D z[n][D] x[s][D] ---
        floatx4 C = {0.f, 0.f, 0.f, 0.f};
        #pragma unroll
        for (int k = 0; k < 8; ++k) {
          const short8 A = *(const short8*)(zb + l15 * 264 + (k << 5) + (l4 << 3));
          const float* xp = xb + (s0 + l15) * D_ + (k << 5) + (l4 << 3);
          const float4 xv0 = *(const float4*)xp;
          const float4 xv1 = *(const float4*)(xp + 4);
          short8 Bf;
          Bf[0] = (short)f2b(xv0.x); Bf[1] = (short)f2b(xv0.y);
          Bf[2] = (short)f2b(xv0.z); Bf[3] = (short)f2b(xv0.w);
          Bf[4] = (short)f2b(xv1.x); Bf[5] = (short)f2b(xv1.y);
          Bf[6] = (short)f2b(xv1.z); Bf[7] = (short)f2b(xv1.w);
          C = __builtin_amdgcn_mfma_f32_16x16x32_bf16(A, Bf, C, 0, 0, 0);
        }
        // --- softmax over n within tile: C[rg] = b[n=l4*4+rg][s=s0+l15] ---
        float m = fmaxf(fmaxf(C[0], C[1]), fmaxf(C[2], C[3]));
        m = fmaxf(m, __shfl_xor(m, 16, 64));
        m = fmaxf(m, __shfl_xor(m, 32, 64));
        float e0 = __expf(C[0] - m), e1 = __expf(C[1] - m);
        float e2 = __expf(C[2] - m), e3 = __expf(C[3] - m);
        float sm = e0 + e1 + e2 + e3;
        sm += __shfl_xor(sm, 16, 64);
        sm += __shfl_xor(sm, 32, 64);
        const float inv = 1.f / sm;
        // ctileT[s=l15][n=l4*4+rg]
        *(float4*)(ct + l15 * 16 + (l4 << 2)) = make_float4(e0*inv, e1*inv, e2*inv, e3*inv);
        __asm__ volatile("s_waitcnt lgkmcnt(0)" ::: "memory");  // wave-wide LDS RAW
        // --- y-accum: lane owns D-quad; x tile re-read is L1-hot ---
        #pragma unroll 4
        for (int s = 0; s < 16; ++s) {
          const float4 xv = *(const float4*)(xb + (s0 + s) * D_ + (lane << 2));
          const float4 c0 = *(const float4*)(ct + s * 16);
          const float4 c1 = *(const float4*)(ct + s * 16 + 4);
          const float4 c2 = *(const float4*)(ct + s * 16 + 8);
          const float4 c3 = *(const float4*)(ct + s * 16 + 12);
          float cf[16];
          cf[0]=c0.x;  cf[1]=c0.y;  cf[2]=c0.z;  cf[3]=c0.w;
          cf[4]=c1.x;  cf[5]=c1.y;  cf[6]=c1.z;  cf[7]=c1.w;
          cf[8]=c2.x;  cf[9]=c2.y;  cf[10]=c2.z; cf[11]=c2.w;
          cf[12]=c3.x; cf[13]=c3.y; cf[14]=c3.z; cf[15]=c3.w;
          #pragma unroll
          for (int n = 0; n < 16; ++n) {
            yacc[n][0] += cf[n] * xv.x; yacc[n][1] += cf[n] * xv.y;
            yacc[n][2] += cf[n] * xv.z; yacc[n][3] += cf[n] * xv.w;
          }
        }
      }
      // --- cross-wave y reduction: ds_add_f32, j rotated so all 32 banks hit 2-way ---
      #pragma unroll
      for (int jj = 0; jj < 4; ++jj) {
        const int j = ((lane >> 3) + jj) & 3;
        #pragma unroll
        for (int n = 0; n < 16; ++n)
          atomicAdd(&ytmp[n * 260 + (lane << 2) + j], yacc[n][j]);
      }
      __syncthreads();
    }

    // ---- outputs[n][d] = sum_D y[n][D] * W[D][n*32+d], then squash over d ----
    {
      const int o = tid;
      const int n = o >> 5;
      float a = 0.f;
      for (int Db = 0; Db < 32; ++Db) {
        const float4 y0 = *(const float4*)(ytmp + n * 260 + (Db << 3));
        const float4 y1 = *(const float4*)(ytmp + n * 260 + (Db << 3) + 4);
        const float* wp = W + (size_t)(Db << 3) * O_ + o;   // coalesced over o
        a += y0.x * wp[0 * O_]; a += y0.y * wp[1 * O_];
        a += y0.z * wp[2 * O_]; a += y0.w * wp[3 * O_];
        a += y1.x * wp[4 * O_]; a += y1.y * wp[5 * O_];
        a += y1.z * wp[6 * O_]; a += y1.w * wp[7 * O_];
      }
      float ss = a * a;
      #pragma unroll
      for (int off = 1; off < 32; off <<= 1) ss += __shfl_xor(ss, off, 64);
      const float v = a / sqrtf(ss + 1e-7f);
      outp[o] = v;
      if (it == 2) out[(size_t)blockIdx.x * O_ + o] = v;
    }
    __syncthreads();

    if (it < 2) {
      // ---- z[n][D] = sum_d W[D][n*32+d] * outputs[n][d]; wave owns 32 D-rows ----
      const int obase = lane << 3;
      const int n_ln  = lane >> 2;
      float ov[8];
      #pragma unroll
      for (int jq = 0; jq < 8; ++jq) ov[jq] = outp[obase + jq];
      for (int r = 0; r < 32; ++r) {
        const int Dd = (wave << 5) + r;
        const float4 w0 = *(const float4*)(W + (size_t)Dd * O_ + obase);
        const float4 w1 = *(const float4*)(W + (size_t)Dd * O_ + obase + 4);
        float a = w0.x * ov[0] + w0.y * ov[1] + w0.z * ov[2] + w0.w * ov[3]
                + w1.x * ov[4] + w1.y * ov[5] + w1.z * ov[6] + w1.w * ov[7];
        a += __shfl_xor(a, 1, 64);
        a += __shfl_xor(a, 2, 64);
        if ((lane & 3) == 0) zb[n_ln * 264 + Dd] = f2b(a);
      }
      __syncthreads();
    }
  }
}

extern "C" void kernel_launch(void* const* d_in, const int* in_sizes, int n_in,
                              void* d_out, int out_size, void* d_ws, size_t ws_size,
                              hipStream_t stream) {
  const float* x = (const float*)d_in[0];   // [256, 512, 256] f32
  const float* W = (const float*)d_in[1];   // [256, 512] f32
  float* out = (float*)d_out;               // [256*512] f32
  (void)in_sizes; (void)n_in; (void)out_size; (void)d_ws; (void)ws_size;
  caps_kernel<<<256, 512, 0, stream>>>(x, W, out);
}

// Round 7
// 377.770 us; speedup vs baseline: 1.0082x; 1.0082x over previous
//
#include <hip/hip_runtime.h>

// Caps layer: B=256 batches, S=512 input caps, D=256 in-dim, NC=16, DC=32, O=512.
// One block per batch, 512 threads (8 waves); grid 256 = 1 block/CU.
// Fully-fused factorized routing (u_hat and full b never materialized):
//   per routing iter (single x-stream):  per 16-s tile:
//     b_tile[16n x 16s] = z * x^T        (MFMA 16x16x32 bf16, fp32 acc)
//     c_tile = softmax_n(b_tile)         (4-lane shfl over C-fragment)
//     y[n][D] += sum_{s in tile} c[n][s] x[s][D]   (x re-read is L1-hot)
//   then: outputs = squash(y . W), z = W . outputs, repeat.
// x streamed exactly 3x (iter0 rowsum + 2 fused passes) - algorithmic minimum.
// LESSON (r4, r6): any runtime-variable subscript into a register array
// (yacc[n][j] with runtime j) forces a scratch spill -> >100 MB WRITE_SIZE.
// All register-array indices below are compile-time constants.

#define S_ 512
#define D_ 256
#define O_ 512

typedef __attribute__((ext_vector_type(8))) short short8;
typedef __attribute__((ext_vector_type(4))) float floatx4;

__device__ __forceinline__ unsigned short f2b(float f) {
  union { float ff; unsigned int i; } v; v.ff = f;
  unsigned int u = v.i;
  return (unsigned short)((u + 0x7FFFu + ((u >> 16) & 1u)) >> 16);
}

__global__ __launch_bounds__(512, 2) void caps_kernel(
    const float* __restrict__ x, const float* __restrict__ W,
    float* __restrict__ out)
{
  // LDS (~35 KB):
  //   bl   f32 8x256  =  8192 B: per-wave ctileT[16s][16n] | iter0 rowsum strips
  //   ytmp f32 16x260 = 16640 B: y[n][D] (ds_add reduction target)
  //   zb   u16 16x264 =  8448 B: z bf16 (528 B rows, 16B-aligned)
  //   outp f32 512    =  2048 B
  __shared__ __align__(16) float bl[8 * 256];
  __shared__ __align__(16) float ytmp[16 * 260];
  __shared__ __align__(16) unsigned short zb[16 * 264];
  __shared__ __align__(16) float outp[O_];

  const int tid  = threadIdx.x;
  const int wave = tid >> 6;
  const int lane = tid & 63;
  const int l15  = lane & 15, l4 = lane >> 4;
  const float* xb = x + (size_t)blockIdx.x * (S_ * D_);
  float* ct = bl + wave * 256;   // per-wave c-tile [16s][16n] f32

  for (int it = 0; it < 3; ++it) {
    if (it == 0) {
      // ---- iter 0: b=0 -> c=1/16 -> y[n][:] = (1/16)*rowsum(x), all n equal ----
      float a0 = 0.f, a1 = 0.f, a2 = 0.f, a3 = 0.f;
      #pragma unroll 4
      for (int r = 0; r < 64; ++r) {
        const int s = (wave << 6) + r;
        const float4 xv = *(const float4*)(xb + s * D_ + (lane << 2));
        a0 += xv.x; a1 += xv.y; a2 += xv.z; a3 += xv.w;
      }
      *(float4*)(bl + wave * 256 + (lane << 2)) = make_float4(a0, a1, a2, a3);
      __syncthreads();
      if (tid < 256) {
        float v = 0.f;
        #pragma unroll
        for (int w = 0; w < 8; ++w) v += bl[w * 256 + tid];
        v *= 0.0625f;
        #pragma unroll
        for (int n = 0; n < 16; ++n) ytmp[n * 260 + tid] = v;
      }
      __syncthreads();
    } else {
      // ---- fused pass: MFMA b-tile -> softmax -> y-accum; single x stream ----
      for (int i = tid; i < 16 * 260; i += 512) ytmp[i] = 0.f;
      __syncthreads();

      float yacc[16][4];
      #pragma unroll
      for (int n = 0; n < 16; ++n) { yacc[n][0]=0.f; yacc[n][1]=0.f; yacc[n][2]=0.f; yacc[n][3]=0.f; }

      for (int t = 0; t < 4; ++t) {
        const int s0 = (wave << 6) + (t << 4);
        // --- b tile: b[n][s] = sum_D z[n][D] x[s][D] ---
        floatx4 C = {0.f, 0.f, 0.f, 0.f};
        #pragma unroll
        for (int k = 0; k < 8; ++k) {
          const short8 A = *(const short8*)(zb + l15 * 264 + (k << 5) + (l4 << 3));
          const float* xp = xb + (s0 + l15) * D_ + (k << 5) + (l4 << 3);
          const float4 xv0 = *(const float4*)xp;
          const float4 xv1 = *(const float4*)(xp + 4);
          short8 Bf;
          Bf[0] = (short)f2b(xv0.x); Bf[1] = (short)f2b(xv0.y);
          Bf[2] = (short)f2b(xv0.z); Bf[3] = (short)f2b(xv0.w);
          Bf[4] = (short)f2b(xv1.x); Bf[5] = (short)f2b(xv1.y);
          Bf[6] = (short)f2b(xv1.z); Bf[7] = (short)f2b(xv1.w);
          C = __builtin_amdgcn_mfma_f32_16x16x32_bf16(A, Bf, C, 0, 0, 0);
        }
        // --- softmax over n within tile: C[rg] = b[n=l4*4+rg][s=s0+l15] ---
        float m = fmaxf(fmaxf(C[0], C[1]), fmaxf(C[2], C[3]));
        m = fmaxf(m, __shfl_xor(m, 16, 64));
        m = fmaxf(m, __shfl_xor(m, 32, 64));
        float e0 = __expf(C[0] - m), e1 = __expf(C[1] - m);
        float e2 = __expf(C[2] - m), e3 = __expf(C[3] - m);
        float sm = e0 + e1 + e2 + e3;
        sm += __shfl_xor(sm, 16, 64);
        sm += __shfl_xor(sm, 32, 64);
        const float inv = 1.f / sm;
        // ctileT[s=l15][n=l4*4+rg]
        *(float4*)(ct + l15 * 16 + (l4 << 2)) = make_float4(e0*inv, e1*inv, e2*inv, e3*inv);
        __asm__ volatile("s_waitcnt lgkmcnt(0)" ::: "memory");  // wave-wide LDS RAW
        // --- y-accum: lane owns D-quad; x tile re-read is L1-hot ---
        #pragma unroll 4
        for (int s = 0; s < 16; ++s) {
          const float4 xv = *(const float4*)(xb + (s0 + s) * D_ + (lane << 2));
          const float4 c0 = *(const float4*)(ct + s * 16);
          const float4 c1 = *(const float4*)(ct + s * 16 + 4);
          const float4 c2 = *(const float4*)(ct + s * 16 + 8);
          const float4 c3 = *(const float4*)(ct + s * 16 + 12);
          float cf[16];
          cf[0]=c0.x;  cf[1]=c0.y;  cf[2]=c0.z;  cf[3]=c0.w;
          cf[4]=c1.x;  cf[5]=c1.y;  cf[6]=c1.z;  cf[7]=c1.w;
          cf[8]=c2.x;  cf[9]=c2.y;  cf[10]=c2.z; cf[11]=c2.w;
          cf[12]=c3.x; cf[13]=c3.y; cf[14]=c3.z; cf[15]=c3.w;
          #pragma unroll
          for (int n = 0; n < 16; ++n) {
            yacc[n][0] += cf[n] * xv.x; yacc[n][1] += cf[n] * xv.y;
            yacc[n][2] += cf[n] * xv.z; yacc[n][3] += cf[n] * xv.w;
          }
        }
      }
      // --- cross-wave y reduction: ds_add_f32 with COMPILE-TIME register indices.
      // (8-way bank conflict per instruction; 64 atomics/thread ~ few us, vs the
      // 90 us the r6 dynamic-index spill cost.)
      #pragma unroll
      for (int n = 0; n < 16; ++n) {
        atomicAdd(&ytmp[n * 260 + (lane << 2) + 0], yacc[n][0]);
        atomicAdd(&ytmp[n * 260 + (lane << 2) + 1], yacc[n][1]);
        atomicAdd(&ytmp[n * 260 + (lane << 2) + 2], yacc[n][2]);
        atomicAdd(&ytmp[n * 260 + (lane << 2) + 3], yacc[n][3]);
      }
      __syncthreads();
    }

    // ---- outputs[n][d] = sum_D y[n][D] * W[D][n*32+d], then squash over d ----
    {
      const int o = tid;
      const int n = o >> 5;
      float a = 0.f;
      for (int Db = 0; Db < 32; ++Db) {
        const float4 y0 = *(const float4*)(ytmp + n * 260 + (Db << 3));
        const float4 y1 = *(const float4*)(ytmp + n * 260 + (Db << 3) + 4);
        const float* wp = W + (size_t)(Db << 3) * O_ + o;   // coalesced over o
        a += y0.x * wp[0 * O_]; a += y0.y * wp[1 * O_];
        a += y0.z * wp[2 * O_]; a += y0.w * wp[3 * O_];
        a += y1.x * wp[4 * O_]; a += y1.y * wp[5 * O_];
        a += y1.z * wp[6 * O_]; a += y1.w * wp[7 * O_];
      }
      float ss = a * a;
      #pragma unroll
      for (int off = 1; off < 32; off <<= 1) ss += __shfl_xor(ss, off, 64);
      const float v = a / sqrtf(ss + 1e-7f);
      outp[o] = v;
      if (it == 2) out[(size_t)blockIdx.x * O_ + o] = v;
    }
    __syncthreads();

    if (it < 2) {
      // ---- z[n][D] = sum_d W[D][n*32+d] * outputs[n][d]; wave owns 32 D-rows ----
      const int obase = lane << 3;
      const int n_ln  = lane >> 2;
      float ov[8];
      #pragma unroll
      for (int jq = 0; jq < 8; ++jq) ov[jq] = outp[obase + jq];
      for (int r = 0; r < 32; ++r) {
        const int Dd = (wave << 5) + r;
        const float4 w0 = *(const float4*)(W + (size_t)Dd * O_ + obase);
        const float4 w1 = *(const float4*)(W + (size_t)Dd * O_ + obase + 4);
        float a = w0.x * ov[0] + w0.y * ov[1] + w0.z * ov[2] + w0.w * ov[3]
                + w1.x * ov[4] + w1.y * ov[5] + w1.z * ov[6] + w1.w * ov[7];
        a += __shfl_xor(a, 1, 64);
        a += __shfl_xor(a, 2, 64);
        if ((lane & 3) == 0) zb[n_ln * 264 + Dd] = f2b(a);
      }
      __syncthreads();
    }
  }
}

extern "C" void kernel_launch(void* const* d_in, const int* in_sizes, int n_in,
                              void* d_out, int out_size, void* d_ws, size_t ws_size,
                              hipStream_t stream) {
  const float* x = (const float*)d_in[0];   // [256, 512, 256] f32
  const float* W = (const float*)d_in[1];   // [256, 512] f32
  float* out = (float*)d_out;               // [256*512] f32
  (void)in_sizes; (void)n_in; (void)out_size; (void)d_ws; (void)ws_size;
  caps_kernel<<<256, 512, 0, stream>>>(x, W, out);
}